// Round 6
// baseline (252.870 us; speedup 1.0000x reference)
//
#include <hip/hip_runtime.h>

// ContinuousConv: N=200000, M=100000, CIN=32, COUT=64, K=32, KS=3
// Round 6: two-unit pipeline per block (units blk, blk+3125). vmcnt-aware issue
// order keeps next-unit feature gathers outstanding under CQ0 + PHASE2(u0).

typedef __attribute__((ext_vector_type(8))) __bf16 bf16x8;
typedef __attribute__((ext_vector_type(4))) __bf16 bf16x4;
typedef __attribute__((ext_vector_type(4))) float f32x4;
typedef unsigned int u32;
typedef unsigned short u16;

constexpr int NPTS = 200000;
constexpr int MPTS = 100000;
constexpr int MB   = 16;                  // points per unit
constexpr int NUNIT = MPTS / MB;          // 6250
constexpr int NBLK  = NUNIT / 2;          // 3125 blocks, units blk & blk+NBLK

constexpr int W_V       = 72;             // bytes per voxel row (36 bf16 slots)
constexpr int PT_STRIDE = 2016;           // 28 rows * 72 B; also covers acc 1792+swz
constexpr int NRM_OFF   = MB * PT_STRIDE; // 32256
constexpr int LDS_BYTES = NRM_OFF + 64;   // 32320 -> 32KB granule

// d_ws: Wfrag bf16 [4 nt][28 ks][64 lane][8] = 114688 B, then feats bf16 [N][32]
constexpr size_t WFRAG_ELEMS = 4 * 28 * 64 * 8;
constexpr size_t FEATS_OFF_ELEMS = WFRAG_ELEMS;
constexpr size_t WS_NEED = (WFRAG_ELEMS + (size_t)NPTS * 32) * 2;

__global__ void prep_kernel(const float* __restrict__ kern,
                            const float* __restrict__ feats,
                            __bf16* __restrict__ wsb) {
    const int blk = blockIdx.x;
    if (blk < 224) {
        const int tid = blk * 256 + threadIdx.x;
        const int j  = tid & 7;
        const int l  = (tid >> 3) & 63;
        const int s  = tid >> 9;
        const int ks = s % 28;
        const int nt = s / 28;
        const int kk = ks * 32 + ((l >> 4) << 3) + j;
        const int ch = kk / 28;
        const int v  = kk - ch * 28;
        const int o  = nt * 16 + (l & 15);
        const float val = (v < 27) ? kern[v * 2048 + ch * 64 + o] : 0.0f;
        wsb[tid] = (__bf16)val;
    } else {
        const int t = (blk - 224) * 256 + threadIdx.x;
        const float4* src = (const float4*)feats + (size_t)t * 2;
        const float4 a = src[0];
        const float4 b = src[1];
        bf16x8 o;
        o[0]=(__bf16)a.x; o[1]=(__bf16)a.y; o[2]=(__bf16)a.z; o[3]=(__bf16)a.w;
        o[4]=(__bf16)b.x; o[5]=(__bf16)b.y; o[6]=(__bf16)b.z; o[7]=(__bf16)b.w;
        *(bf16x8*)(wsb + FEATS_OFF_ELEMS + (size_t)t * 8) = o;
    }
}

// ---------------- phase 0: loads / math split ----------------
struct P0R {
    int2 nn;
    float ox, oy, oz;
    float pax, pay, paz, pbx, pby, pbz;
    float ia, ib;
};

__device__ __forceinline__ P0R p0_load(int m_base, int tid,
    const int* __restrict__ nbrs, const float* __restrict__ outpos,
    const float* __restrict__ inpos, const float* __restrict__ importance)
{
    P0R r;
    const int pt = tid >> 4, kp = tid & 15;
    const int m  = m_base + pt;
    r.nn = *(const int2*)(nbrs + m * 32 + 2 * kp);
    r.ox = outpos[3 * m + 0]; r.oy = outpos[3 * m + 1]; r.oz = outpos[3 * m + 2];
    r.pax = inpos[3 * r.nn.x + 0]; r.pay = inpos[3 * r.nn.x + 1]; r.paz = inpos[3 * r.nn.x + 2];
    r.pbx = inpos[3 * r.nn.y + 0]; r.pby = inpos[3 * r.nn.y + 1]; r.pbz = inpos[3 * r.nn.y + 2];
    r.ia = importance[r.nn.x];
    r.ib = importance[r.nn.y];
    return r;
}

__device__ __forceinline__ void p0_math(const P0R& r, unsigned char* smem,
                                        float* nrm, int tid, float inv_r)
{
    const int pt = tid >> 4, kp = tid & 15;

    float cxA, cyA, czA, impA, cxB, cyB, czB, impB;
    {
        const float rx = (r.pax - r.ox) * inv_r;
        const float ry = (r.pay - r.oy) * inv_r;
        const float rz = (r.paz - r.oz) * inv_r;
        const float dist = sqrtf(rx * rx + ry * ry + rz * rz);
        impA = (dist <= 1.0f) ? r.ia : 0.0f;
        const float linf = fmaxf(fabsf(rx), fmaxf(fabsf(ry), fabsf(rz)));
        const float sc = (linf > 1e-8f) ? (dist / linf) : 0.0f;
        cxA = fminf(fmaxf(rx * sc + 1.0f, 0.0f), 2.0f);
        cyA = fminf(fmaxf(ry * sc + 1.0f, 0.0f), 2.0f);
        czA = fminf(fmaxf(rz * sc + 1.0f, 0.0f), 2.0f);
    }
    {
        const float rx = (r.pbx - r.ox) * inv_r;
        const float ry = (r.pby - r.oy) * inv_r;
        const float rz = (r.pbz - r.oz) * inv_r;
        const float dist = sqrtf(rx * rx + ry * ry + rz * rz);
        impB = (dist <= 1.0f) ? r.ib : 0.0f;
        const float linf = fmaxf(fabsf(rx), fmaxf(fabsf(ry), fabsf(rz)));
        const float sc = (linf > 1e-8f) ? (dist / linf) : 0.0f;
        cxB = fminf(fmaxf(rx * sc + 1.0f, 0.0f), 2.0f);
        cyB = fminf(fmaxf(ry * sc + 1.0f, 0.0f), 2.0f);
        czB = fminf(fmaxf(rz * sc + 1.0f, 0.0f), 2.0f);
    }

    float wxA[3], wyA[3], wzA[3], wxB[3], wyB[3], wzB[3];
    wxA[0] = fmaxf(0.f, 1.f - cxA) * impA;
    wxA[1] = (1.f - fabsf(cxA - 1.f)) * impA;
    wxA[2] = fmaxf(0.f, cxA - 1.f) * impA;
    wyA[0] = fmaxf(0.f, 1.f - cyA); wyA[1] = 1.f - fabsf(cyA - 1.f); wyA[2] = fmaxf(0.f, cyA - 1.f);
    wzA[0] = fmaxf(0.f, 1.f - czA); wzA[1] = 1.f - fabsf(czA - 1.f); wzA[2] = fmaxf(0.f, czA - 1.f);
    wxB[0] = fmaxf(0.f, 1.f - cxB) * impB;
    wxB[1] = (1.f - fabsf(cxB - 1.f)) * impB;
    wxB[2] = fmaxf(0.f, cxB - 1.f) * impB;
    wyB[0] = fmaxf(0.f, 1.f - cyB); wyB[1] = 1.f - fabsf(cyB - 1.f); wyB[2] = fmaxf(0.f, cyB - 1.f);
    wzB[0] = fmaxf(0.f, 1.f - czB); wzB[1] = 1.f - fabsf(czB - 1.f); wzB[2] = fmaxf(0.f, czB - 1.f);

    unsigned char* wrow = smem + pt * PT_STRIDE + kp * 4;
#pragma unroll
    for (int a = 0; a < 3; ++a)
#pragma unroll
        for (int b = 0; b < 3; ++b) {
            const float pA = wxA[a] * wyA[b];
            const float pB = wxB[a] * wyB[b];
#pragma unroll
            for (int c = 0; c < 3; ++c) {
                const int v = a * 9 + b * 3 + c;
                union { __bf16 h[2]; u32 u; } pk;
                pk.h[0] = (__bf16)(pA * wzA[c]);
                pk.h[1] = (__bf16)(pB * wzB[c]);
                *(u32*)(wrow + v * W_V) = pk.u;
            }
        }
    *(u32*)(wrow + 27 * W_V) = 0u;

    float s = impA + impB;
    s += __shfl_xor(s, 1);
    s += __shfl_xor(s, 2);
    s += __shfl_xor(s, 4);
    s += __shfl_xor(s, 8);
    if (kp == 0) nrm[pt] = (s > 0.f) ? (1.f / fmaxf(s, 1e-12f)) : 0.f;
}

// ---------------- phase 1 helpers ----------------
__device__ __forceinline__ void sq_batch(u32 dst[8], const u32* __restrict__ featsb,
                                         const int* __restrict__ nb, int lr)
{
    const int4 nA = *(const int4*)(nb);
    const int4 nB = *(const int4*)(nb + 4);
    dst[0] = featsb[(size_t)nA.x * 16 + lr];
    dst[1] = featsb[(size_t)nA.y * 16 + lr];
    dst[2] = featsb[(size_t)nA.z * 16 + lr];
    dst[3] = featsb[(size_t)nA.w * 16 + lr];
    dst[4] = featsb[(size_t)nB.x * 16 + lr];
    dst[5] = featsb[(size_t)nB.y * 16 + lr];
    dst[6] = featsb[(size_t)nB.z * 16 + lr];
    dst[7] = featsb[(size_t)nB.w * 16 + lr];
}

__device__ __forceinline__ void compute_pt(
    unsigned char* smem, int ptq, int lr, int grp, bf16x8 b0, bf16x8 b1)
{
    unsigned char* pbase = smem + ptq * PT_STRIDE;
    const u32 sw = ((u32)(ptq & 7)) << 4;
    const bf16x8 a0 = *(const bf16x8*)(pbase + lr * W_V + grp * 16);
    const int rr = (16 + lr > 27) ? 27 : (16 + lr);      // clamp to zero pad row
    const bf16x8 a1 = *(const bf16x8*)(pbase + rr * W_V + grp * 16);

    f32x4 d00 = {0.f,0.f,0.f,0.f}, d01 = {0.f,0.f,0.f,0.f};
    f32x4 d10 = {0.f,0.f,0.f,0.f}, d11 = {0.f,0.f,0.f,0.f};
    d00 = __builtin_amdgcn_mfma_f32_16x16x32_bf16(a0, b0, d00, 0, 0, 0);
    d01 = __builtin_amdgcn_mfma_f32_16x16x32_bf16(a0, b1, d01, 0, 0, 0);
    d10 = __builtin_amdgcn_mfma_f32_16x16x32_bf16(a1, b0, d10, 0, 0, 0);
    d11 = __builtin_amdgcn_mfma_f32_16x16x32_bf16(a1, b1, d11, 0, 0, 0);

    const int vb0 = grp * 4, vb1 = 16 + grp * 4;
    bf16x4 t;
    t[0]=(__bf16)d00[0]; t[1]=(__bf16)d00[1]; t[2]=(__bf16)d00[2]; t[3]=(__bf16)d00[3];
    *(bf16x4*)(pbase + (((u32)(112 * lr + 2 * vb0)) ^ sw)) = t;
    t[0]=(__bf16)d01[0]; t[1]=(__bf16)d01[1]; t[2]=(__bf16)d01[2]; t[3]=(__bf16)d01[3];
    *(bf16x4*)(pbase + (((u32)(112 * lr + 56 + 2 * vb0)) ^ sw)) = t;
    if (vb1 < 28) {
        t[0]=(__bf16)d10[0]; t[1]=(__bf16)d10[1]; t[2]=(__bf16)d10[2]; t[3]=(__bf16)d10[3];
        *(bf16x4*)(pbase + (((u32)(112 * lr + 2 * vb1)) ^ sw)) = t;
        t[0]=(__bf16)d11[0]; t[1]=(__bf16)d11[1]; t[2]=(__bf16)d11[2]; t[3]=(__bf16)d11[3];
        *(bf16x4*)(pbase + (((u32)(112 * lr + 56 + 2 * vb1)) ^ sw)) = t;
    }
}

__device__ __forceinline__ void cq_pt(unsigned char* smem, int ptq, int lr, int grp,
                                      const u32 s[8])
{
    union { u16 u[8]; bf16x8 v; } B0, B1;
#pragma unroll
    for (int j = 0; j < 8; ++j) {
        B0.u[j] = (u16)(s[j] & 0xffffu);
        B1.u[j] = (u16)(s[j] >> 16);
    }
    compute_pt(smem, ptq, lr, grp, B0.v, B1.v);
}

// ---------------- phase 2: out = acc . W (depth-2 W ring, JIT LDS A) --------
__device__ __forceinline__ void phase2_run(
    const unsigned char* smem, const float* nrm,
    const __bf16* __restrict__ wfrag, const float* __restrict__ bias,
    float* __restrict__ out, int m_base, int wv, int lane, int grp, int lr)
{
    const bf16x8* wb = (const bf16x8*)wfrag;
    const size_t wvb = (size_t)(wv * 28) * 64 + lane;
    const unsigned char* abase = smem + lr * PT_STRIDE;
    const u32 swr = ((u32)(lr & 7)) << 4;

    bf16x8 w0 = wb[wvb];
    bf16x8 w1 = wb[wvb + 64];
    f32x4 e = {0.f, 0.f, 0.f, 0.f};
#pragma unroll
    for (int ks = 0; ks < 28; ++ks) {
        const bf16x8 a = *(const bf16x8*)(abase + (((u32)(ks * 64 + grp * 16)) ^ swr));
        e = __builtin_amdgcn_mfma_f32_16x16x32_bf16(a, (ks & 1) ? w1 : w0, e, 0, 0, 0);
        if (ks + 2 < 28) {
            if (ks & 1) w1 = wb[wvb + (size_t)(ks + 2) * 64];
            else        w0 = wb[wvb + (size_t)(ks + 2) * 64];
        }
    }

    const int o = wv * 16 + lr;
    const float bb = bias[o];
#pragma unroll
    for (int r = 0; r < 4; ++r) {
        const int pt = grp * 4 + r;
        out[(size_t)(m_base + pt) * 64 + o] = e[r] * nrm[pt] + bb;
    }
}

// ---------------- pipelined PRE kernel ----------------
__global__ __launch_bounds__(256, 4)
void cconv_pipe(const u32* __restrict__ featsb,
                const float* __restrict__ inpos,
                const float* __restrict__ outpos,
                const float* __restrict__ extents,
                const float* __restrict__ importance,
                const int*   __restrict__ nbrs,
                const __bf16* __restrict__ wfrag,
                const float* __restrict__ bias,
                float* __restrict__ out)
{
    __shared__ __align__(16) unsigned char smem[LDS_BYTES];
    const int tid = threadIdx.x;
    const int blk = blockIdx.x;
    float* nrm = (float*)(smem + NRM_OFF);
    const float inv_r = 2.0f / extents[0];

    const int wv = tid >> 6, lane = tid & 63, grp = lane >> 4, lr = lane & 15;
    const int m0 = blk * MB;
    const int m1 = (blk + NBLK) * MB;
    const int* nb0 = nbrs + (m0 + wv * 4) * 32 + grp * 8;
    const int* nb1 = nbrs + (m1 + wv * 4) * 32 + grp * 8;

    // ---- unit0 phase0 loads (oldest vmem: waits on these don't drain SQ) ----
    const P0R r0 = p0_load(m0, tid, nbrs, outpos, inpos, importance);

    // ---- SQ0 then SQ1: all 64 feature gathers in flight ----
    u32 stq0[4][8], stq1[4][8];
    sq_batch(stq0[0], featsb, nb0 +  0, lr);
    sq_batch(stq0[1], featsb, nb0 + 32, lr);
    sq_batch(stq0[2], featsb, nb0 + 64, lr);
    sq_batch(stq0[3], featsb, nb0 + 96, lr);
    sq_batch(stq1[0], featsb, nb1 +  0, lr);
    sq_batch(stq1[1], featsb, nb1 + 32, lr);
    sq_batch(stq1[2], featsb, nb1 + 64, lr);
    sq_batch(stq1[3], featsb, nb1 + 96, lr);
    __builtin_amdgcn_sched_barrier(0);    // pin: all gathers issued before compute

    // ---- unit0 phase0 math (+ LDS w writes), then CQ0 (consumes stq0) ----
    p0_math(r0, smem, nrm, tid, inv_r);
    cq_pt(smem, wv * 4 + 0, lr, grp, stq0[0]);
    cq_pt(smem, wv * 4 + 1, lr, grp, stq0[1]);
    cq_pt(smem, wv * 4 + 2, lr, grp, stq0[2]);
    cq_pt(smem, wv * 4 + 3, lr, grp, stq0[3]);
    __syncthreads();

    // ---- unit0 GEMM (SQ1 still in flight for its first iterations) ----
    phase2_run(smem, nrm, wfrag, bias, out, m0, wv, lane, grp, lr);
    __syncthreads();

    // ---- unit1: phase0 (loads+math), CQ1 (stq1 arrived long ago) ----
    const P0R r1 = p0_load(m1, tid, nbrs, outpos, inpos, importance);
    p0_math(r1, smem, nrm, tid, inv_r);
    cq_pt(smem, wv * 4 + 0, lr, grp, stq1[0]);
    cq_pt(smem, wv * 4 + 1, lr, grp, stq1[1]);
    cq_pt(smem, wv * 4 + 2, lr, grp, stq1[2]);
    cq_pt(smem, wv * 4 + 3, lr, grp, stq1[3]);
    __syncthreads();

    // ---- unit1 GEMM ----
    phase2_run(smem, nrm, wfrag, bias, out, m1, wv, lane, grp, lr);
}

// ---------------- F32 fallback (r5 structure, non-pipelined) ----------------
__global__ __launch_bounds__(256, 4)
void cconv_f32(const float* __restrict__ feats,
               const float* __restrict__ inpos,
               const float* __restrict__ outpos,
               const float* __restrict__ extents,
               const float* __restrict__ importance,
               const int*   __restrict__ nbrs,
               const __bf16* __restrict__ wfrag,
               const float* __restrict__ bias,
               float* __restrict__ out)
{
    __shared__ __align__(16) unsigned char smem[LDS_BYTES];
    const int tid = threadIdx.x;
    const int blk = blockIdx.x;
    float* nrm = (float*)(smem + NRM_OFF);
    const float inv_r = 2.0f / extents[0];

    const int wv = tid >> 6, lane = tid & 63, grp = lane >> 4, lr = lane & 15;
    const int m0 = blk * MB;
    const int* nb_base = nbrs + (m0 + wv * 4) * 32 + grp * 8;

    const P0R r0 = p0_load(m0, tid, nbrs, outpos, inpos, importance);
    p0_math(r0, smem, nrm, tid, inv_r);

#pragma unroll
    for (int q = 0; q < 4; ++q) {
        const int4 nA = *(const int4*)(nb_base + q * 32);
        const int4 nB = *(const int4*)(nb_base + q * 32 + 4);
        float2 sf[8];
        sf[0] = ((const float2*)(feats + (size_t)nA.x * 32))[lr];
        sf[1] = ((const float2*)(feats + (size_t)nA.y * 32))[lr];
        sf[2] = ((const float2*)(feats + (size_t)nA.z * 32))[lr];
        sf[3] = ((const float2*)(feats + (size_t)nA.w * 32))[lr];
        sf[4] = ((const float2*)(feats + (size_t)nB.x * 32))[lr];
        sf[5] = ((const float2*)(feats + (size_t)nB.y * 32))[lr];
        sf[6] = ((const float2*)(feats + (size_t)nB.z * 32))[lr];
        sf[7] = ((const float2*)(feats + (size_t)nB.w * 32))[lr];
        bf16x8 b0, b1;
#pragma unroll
        for (int j = 0; j < 8; ++j) {
            b0[j] = (__bf16)sf[j].x;
            b1[j] = (__bf16)sf[j].y;
        }
        compute_pt(smem, wv * 4 + q, lr, grp, b0, b1);
    }
    __syncthreads();
    phase2_run(smem, nrm, wfrag, bias, out, m0, wv, lane, grp, lr);
}

extern "C" void kernel_launch(void* const* d_in, const int* in_sizes, int n_in,
                              void* d_out, int out_size, void* d_ws, size_t ws_size,
                              hipStream_t stream) {
    (void)in_sizes; (void)n_in; (void)out_size;
    const float* feats      = (const float*)d_in[0];
    const float* inpos      = (const float*)d_in[1];
    const float* outpos     = (const float*)d_in[2];
    const float* extents    = (const float*)d_in[3];
    const float* importance = (const float*)d_in[4];
    const int*   nbrs       = (const int*)d_in[5];
    const float* kern       = (const float*)d_in[6];
    const float* bias       = (const float*)d_in[7];
    float* outp = (float*)d_out;
    __bf16* wsb = (__bf16*)d_ws;
    const u32* featsb = (const u32*)(wsb + FEATS_OFF_ELEMS);

    const bool pre = ws_size >= WS_NEED;

    hipLaunchKernelGGL(prep_kernel, dim3(pre ? 3349 : 224), dim3(256), 0, stream,
                       kern, feats, wsb);
    if (pre) {
        hipLaunchKernelGGL(cconv_pipe, dim3(NBLK), dim3(256), 0, stream,
                           featsb, inpos, outpos, extents, importance,
                           nbrs, wsb, bias, outp);
    } else {
        hipLaunchKernelGGL(cconv_f32, dim3(NBLK * 2), dim3(256), 0, stream,
                           feats, inpos, outpos, extents, importance,
                           nbrs, wsb, bias, outp);
    }
}